// Round 3
// baseline (2134.958 us; speedup 1.0000x reference)
//
#include <hip/hip_runtime.h>

#define WG 256
#define BN 128        // nodes per bucket
#define NBMAX 800     // max buckets (N <= 102400)
#define CHUNK 8192    // edges per binning chunk
#define AGG_T 512     // threads in aggregation blocks

// ---------------------------------------------------------------------------
// Edge-index dtype probe: int64 little-endian (values < 2^31) => all odd
// 32-bit words of the first 256 entries are 0.
// ---------------------------------------------------------------------------
__global__ __launch_bounds__(WG) void k_detect(const unsigned int* __restrict__ ei,
                                               int* __restrict__ flag) {
  __shared__ int nz;
  if (threadIdx.x == 0) nz = 0;
  __syncthreads();
  unsigned int w = ei[threadIdx.x * 2 + 1];
  if (w != 0u) atomicAdd(&nz, 1);
  __syncthreads();
  if (threadIdx.x == 0) *flag = (nz == 0) ? 1 : 0;  // 1 => int64 layout
}

// ---------------------------------------------------------------------------
// Per-chunk bucket histogram (LDS atomics only), hist[chunk][NB]
// ---------------------------------------------------------------------------
__global__ __launch_bounds__(WG) void k_hist(const int* __restrict__ ei,
                                             const int* __restrict__ flag,
                                             int* __restrict__ hist, int NB, int E) {
  __shared__ int hc[NBMAX];
  const int c = blockIdx.x;
  for (int b = threadIdx.x; b < NB; b += WG) hc[b] = 0;
  __syncthreads();
  const bool i64 = (*flag != 0);
  const int e0 = c * CHUNK;
  for (int i = 0; i < CHUNK; i += WG) {
    int e = e0 + i + threadIdx.x;
    if (e < E) {
      int d = i64 ? ei[2 * (E + e)] : ei[E + e];
      atomicAdd(&hc[d / BN], 1);
    }
  }
  __syncthreads();
  for (int b = threadIdx.x; b < NB; b += WG) hist[(size_t)c * NB + b] = hc[b];
}

// ---------------------------------------------------------------------------
// Per-bucket exclusive scan over chunks (in place), total -> bucketTotal[b]
// ---------------------------------------------------------------------------
__global__ __launch_bounds__(512) void k_bscan1(int* __restrict__ hist,
                                                int* __restrict__ bucketTotal,
                                                int NB, int NC) {
  __shared__ int sh[512];
  const int b = blockIdx.x;
  int carry = 0;
  for (int c0 = 0; c0 < NC; c0 += 512) {
    int c = c0 + (int)threadIdx.x;
    int v = (c < NC) ? hist[(size_t)c * NB + b] : 0;
    sh[threadIdx.x] = v;
    __syncthreads();
    for (int off = 1; off < 512; off <<= 1) {
      int t = (threadIdx.x >= (unsigned)off) ? sh[threadIdx.x - off] : 0;
      __syncthreads();
      sh[threadIdx.x] += t;
      __syncthreads();
    }
    if (c < NC) hist[(size_t)c * NB + b] = carry + sh[threadIdx.x] - v;
    carry += sh[511];
    __syncthreads();
  }
  if (threadIdx.x == 0) bucketTotal[b] = carry;
}

// exclusive scan of bucketTotal -> bucketBase[0..NB], bucketBase[NB] = E
__global__ __launch_bounds__(1024) void k_bbase(const int* __restrict__ bucketTotal,
                                                int* __restrict__ bucketBase, int NB) {
  __shared__ int sh[1024];
  int carry = 0;
  for (int b0 = 0; b0 < NB; b0 += 1024) {
    int b = b0 + (int)threadIdx.x;
    int v = (b < NB) ? bucketTotal[b] : 0;
    sh[threadIdx.x] = v;
    __syncthreads();
    for (int off = 1; off < 1024; off <<= 1) {
      int t = (threadIdx.x >= (unsigned)off) ? sh[threadIdx.x - off] : 0;
      __syncthreads();
      sh[threadIdx.x] += t;
      __syncthreads();
    }
    if (b < NB) bucketBase[b] = carry + sh[threadIdx.x] - v;
    carry += sh[1023];
    __syncthreads();
  }
  if (threadIdx.x == 0) bucketBase[NB] = carry;
}

// ---------------------------------------------------------------------------
// Multisplit scatter: chunk c writes (src,dst) pairs into its private slice
// of each bucket region. LDS cursors; no global atomics.
// ---------------------------------------------------------------------------
__global__ __launch_bounds__(WG) void k_mscatter(const int* __restrict__ ei,
                                                 const int* __restrict__ flag,
                                                 const int* __restrict__ hist,
                                                 const int* __restrict__ bucketBase,
                                                 int2* __restrict__ pairs,
                                                 int NB, int E) {
  __shared__ int cur[NBMAX];
  const int c = blockIdx.x;
  for (int b = threadIdx.x; b < NB; b += WG)
    cur[b] = bucketBase[b] + hist[(size_t)c * NB + b];
  __syncthreads();
  const bool i64 = (*flag != 0);
  const int e0 = c * CHUNK;
  for (int i = 0; i < CHUNK; i += WG) {
    int e = e0 + i + threadIdx.x;
    if (e < E) {
      int s, d;
      if (i64) { s = ei[2 * e]; d = ei[2 * (E + e)]; }
      else     { s = ei[e];     d = ei[E + e]; }
      int pos = atomicAdd(&cur[d / BN], 1);
      pairs[pos] = make_int2(s, d);
    }
  }
}

// ---------------------------------------------------------------------------
// Per-bucket degree -> dinv (LDS histogram over the bucket's pair list)
// ---------------------------------------------------------------------------
__global__ __launch_bounds__(WG) void k_bdeg(const int2* __restrict__ pairs,
                                             const int* __restrict__ bucketBase,
                                             float* __restrict__ dinv, int N) {
  __shared__ int cnt[BN];
  const int b = blockIdx.x;
  if (threadIdx.x < BN) cnt[threadIdx.x] = 0;
  __syncthreads();
  const int beg = bucketBase[b], end = bucketBase[b + 1];
  for (int e = beg + threadIdx.x; e < end; e += WG)
    atomicAdd(&cnt[pairs[e].y - b * BN], 1);
  __syncthreads();
  int n = b * BN + threadIdx.x;
  if (threadIdx.x < BN && n < N)
    dinv[n] = rsqrtf((float)(cnt[threadIdx.x] + 1));  // +1 = self-loop
}

// ---------------------------------------------------------------------------
// GEMM1: ht1[n][64] = (x[n][128] @ W1[128][64]) * dinv[n]
// ---------------------------------------------------------------------------
__global__ __launch_bounds__(WG) void k_gemm1(const float* __restrict__ x,
                                              const float* __restrict__ W1,
                                              const float* __restrict__ dinv,
                                              float* __restrict__ ht1, int N) {
  __shared__ float xs[64 * 128];
  __shared__ float w1s[128 * 64];
  const int tid = threadIdx.x;
  const int n0 = blockIdx.x * 64;

  for (int v = tid; v < 2048; v += WG)
    *(float4*)&w1s[v * 4] = ((const float4*)W1)[v];
  for (int v = tid; v < 2048; v += WG) {
    int row = v >> 5, c4 = v & 31;
    int n = n0 + row;
    float4 val = make_float4(0.f, 0.f, 0.f, 0.f);
    if (n < N) val = ((const float4*)x)[(size_t)n * 32 + c4];
    *(float4*)&xs[row * 128 + ((c4 ^ ((row >> 2) & 3)) << 2)] = val;
  }
  __syncthreads();

  const int cg = tid & 15;
  const int ng = tid >> 4;
  const int ngm = ng & 3;
  float acc[4][4] = {};

#pragma unroll 4
  for (int k4 = 0; k4 < 32; k4++) {
    float4 xa[4], wv[4];
#pragma unroll
    for (int i = 0; i < 4; i++)
      xa[i] = *(const float4*)&xs[(ng * 4 + i) * 128 + ((k4 ^ ngm) << 2)];
#pragma unroll
    for (int kk = 0; kk < 4; kk++)
      wv[kk] = *(const float4*)&w1s[(k4 * 4 + kk) * 64 + cg * 4];
#pragma unroll
    for (int i = 0; i < 4; i++) {
#pragma unroll
      for (int kk = 0; kk < 4; kk++) {
        float a = (kk == 0) ? xa[i].x : (kk == 1) ? xa[i].y : (kk == 2) ? xa[i].z : xa[i].w;
        acc[i][0] += a * wv[kk].x;
        acc[i][1] += a * wv[kk].y;
        acc[i][2] += a * wv[kk].z;
        acc[i][3] += a * wv[kk].w;
      }
    }
  }

#pragma unroll
  for (int i = 0; i < 4; i++) {
    int n = n0 + ng * 4 + i;
    if (n >= N) continue;
    float dv = dinv[n];
    ((float4*)ht1)[(size_t)n * 16 + cg] = make_float4(
        acc[i][0] * dv, acc[i][1] * dv, acc[i][2] * dv, acc[i][3] * dv);
  }
}

// ---------------------------------------------------------------------------
// Bucketed aggregation, 64 ch: block = bucket, LDS accumulator 128x64.
// acc init = ht[n] (self term); per edge: gather ht[src] row, LDS atomicAdd
// into dst row; writeout agg = acc * dinv.
// ---------------------------------------------------------------------------
__global__ __launch_bounds__(AGG_T) void k_bagg64(const int2* __restrict__ pairs,
                                                  const int* __restrict__ bucketBase,
                                                  const float* __restrict__ dinv,
                                                  const float* __restrict__ ht,
                                                  float* __restrict__ agg, int N) {
  __shared__ float acc[BN * 64];
  const int b = blockIdx.x;
  const int base = b * BN;
  for (int v = threadIdx.x; v < BN * 16; v += AGG_T) {
    int row = v >> 4, c4 = v & 15;
    int n = base + row;
    float4 val = make_float4(0.f, 0.f, 0.f, 0.f);
    if (n < N) val = ((const float4*)ht)[(size_t)n * 16 + c4];
    *(float4*)&acc[row * 64 + c4 * 4] = val;
  }
  __syncthreads();

  const int beg = bucketBase[b], end = bucketBase[b + 1];
  const int wid = threadIdx.x >> 6, lane = threadIdx.x & 63;
  const int NW = AGG_T / 64;
  int e = beg + wid;
  for (; e + 3 * NW < end; e += 4 * NW) {
    int2 p0 = pairs[e];
    int2 p1 = pairs[e + NW];
    int2 p2 = pairs[e + 2 * NW];
    int2 p3 = pairs[e + 3 * NW];
    float v0 = ht[(size_t)p0.x * 64 + lane];
    float v1 = ht[(size_t)p1.x * 64 + lane];
    float v2 = ht[(size_t)p2.x * 64 + lane];
    float v3 = ht[(size_t)p3.x * 64 + lane];
    atomicAdd(&acc[(p0.y - base) * 64 + lane], v0);
    atomicAdd(&acc[(p1.y - base) * 64 + lane], v1);
    atomicAdd(&acc[(p2.y - base) * 64 + lane], v2);
    atomicAdd(&acc[(p3.y - base) * 64 + lane], v3);
  }
  for (; e < end; e += NW) {
    int2 p = pairs[e];
    float v = ht[(size_t)p.x * 64 + lane];
    atomicAdd(&acc[(p.y - base) * 64 + lane], v);
  }
  __syncthreads();

  for (int v = threadIdx.x; v < BN * 16; v += AGG_T) {
    int row = v >> 4, c4 = v & 15;
    int n = base + row;
    if (n < N) {
      float dv = dinv[n];
      float4 a = *(float4*)&acc[row * 64 + c4 * 4];
      ((float4*)agg)[(size_t)n * 16 + c4] =
          make_float4(a.x * dv, a.y * dv, a.z * dv, a.w * dv);
    }
  }
}

// 32-channel variant: half-wave per edge
__global__ __launch_bounds__(AGG_T) void k_bagg32(const int2* __restrict__ pairs,
                                                  const int* __restrict__ bucketBase,
                                                  const float* __restrict__ dinv,
                                                  const float* __restrict__ ht,
                                                  float* __restrict__ agg, int N) {
  __shared__ float acc[BN * 32];
  const int b = blockIdx.x;
  const int base = b * BN;
  for (int v = threadIdx.x; v < BN * 8; v += AGG_T) {
    int row = v >> 3, c4 = v & 7;
    int n = base + row;
    float4 val = make_float4(0.f, 0.f, 0.f, 0.f);
    if (n < N) val = ((const float4*)ht)[(size_t)n * 8 + c4];
    *(float4*)&acc[row * 32 + c4 * 4] = val;
  }
  __syncthreads();

  const int beg = bucketBase[b], end = bucketBase[b + 1];
  const int hw = threadIdx.x >> 5, l = threadIdx.x & 31;
  const int NH = AGG_T / 32;
  int e = beg + hw;
  for (; e + 3 * NH < end; e += 4 * NH) {
    int2 p0 = pairs[e];
    int2 p1 = pairs[e + NH];
    int2 p2 = pairs[e + 2 * NH];
    int2 p3 = pairs[e + 3 * NH];
    float v0 = ht[(size_t)p0.x * 32 + l];
    float v1 = ht[(size_t)p1.x * 32 + l];
    float v2 = ht[(size_t)p2.x * 32 + l];
    float v3 = ht[(size_t)p3.x * 32 + l];
    atomicAdd(&acc[(p0.y - base) * 32 + l], v0);
    atomicAdd(&acc[(p1.y - base) * 32 + l], v1);
    atomicAdd(&acc[(p2.y - base) * 32 + l], v2);
    atomicAdd(&acc[(p3.y - base) * 32 + l], v3);
  }
  for (; e < end; e += NH) {
    int2 p = pairs[e];
    float v = ht[(size_t)p.x * 32 + l];
    atomicAdd(&acc[(p.y - base) * 32 + l], v);
  }
  __syncthreads();

  for (int v = threadIdx.x; v < BN * 8; v += AGG_T) {
    int row = v >> 3, c4 = v & 7;
    int n = base + row;
    if (n < N) {
      float dv = dinv[n];
      float4 a = *(float4*)&acc[row * 32 + c4 * 4];
      ((float4*)agg)[(size_t)n * 8 + c4] =
          make_float4(a.x * dv, a.y * dv, a.z * dv, a.w * dv);
    }
  }
}

// ---------------------------------------------------------------------------
// GEMM2: ht2[n][32] = (relu(agg1[n][64] + b1) @ W2[64][32]) * dinv[n]
// ---------------------------------------------------------------------------
__global__ __launch_bounds__(WG) void k_gemm2(const float* __restrict__ agg1,
                                              const float* __restrict__ b1,
                                              const float* __restrict__ W2,
                                              const float* __restrict__ dinv,
                                              float* __restrict__ ht2, int N) {
  __shared__ float as[64 * 68];
  __shared__ float w2s[64 * 32];
  const int tid = threadIdx.x;
  const int n0 = blockIdx.x * 64;

  for (int v = tid; v < 512; v += WG)
    *(float4*)&w2s[v * 4] = ((const float4*)W2)[v];
  for (int v = tid; v < 1024; v += WG) {
    int row = v >> 4, c4 = v & 15;
    int n = n0 + row;
    float4 val = make_float4(0.f, 0.f, 0.f, 0.f);
    if (n < N) {
      float4 g = ((const float4*)agg1)[(size_t)n * 16 + c4];
      float4 bb = ((const float4*)b1)[c4];
      val.x = fmaxf(g.x + bb.x, 0.f);
      val.y = fmaxf(g.y + bb.y, 0.f);
      val.z = fmaxf(g.z + bb.z, 0.f);
      val.w = fmaxf(g.w + bb.w, 0.f);
    }
    *(float4*)&as[row * 68 + c4 * 4] = val;
  }
  __syncthreads();

  const int cg = tid & 15;
  const int ng = tid >> 4;
  float acc[4][2] = {};

#pragma unroll 4
  for (int k4 = 0; k4 < 16; k4++) {
    float4 xa[4];
    float2 wv[4];
#pragma unroll
    for (int i = 0; i < 4; i++)
      xa[i] = *(const float4*)&as[(ng * 4 + i) * 68 + k4 * 4];
#pragma unroll
    for (int kk = 0; kk < 4; kk++)
      wv[kk] = *(const float2*)&w2s[(k4 * 4 + kk) * 32 + cg * 2];
#pragma unroll
    for (int i = 0; i < 4; i++) {
#pragma unroll
      for (int kk = 0; kk < 4; kk++) {
        float a = (kk == 0) ? xa[i].x : (kk == 1) ? xa[i].y : (kk == 2) ? xa[i].z : xa[i].w;
        acc[i][0] += a * wv[kk].x;
        acc[i][1] += a * wv[kk].y;
      }
    }
  }

#pragma unroll
  for (int i = 0; i < 4; i++) {
    int n = n0 + ng * 4 + i;
    if (n >= N) continue;
    float dv = dinv[n];
    ((float2*)ht2)[(size_t)n * 16 + cg] =
        make_float2(acc[i][0] * dv, acc[i][1] * dv);
  }
}

// ---------------------------------------------------------------------------
// Final head: out[n][2] = (relu(relu(agg2[n]+b2) @ fc_w + fc_b)) @ out_w + out_b
// ---------------------------------------------------------------------------
__global__ __launch_bounds__(WG) void k_final(const float* __restrict__ agg2,
                                              const float* __restrict__ b2,
                                              const float* __restrict__ fc_w,
                                              const float* __restrict__ fc_b,
                                              const float* __restrict__ out_w,
                                              const float* __restrict__ out_b,
                                              float* __restrict__ out, int N) {
  __shared__ float hs[256 * 33];
  __shared__ float fcs[32 * 32];
  __shared__ float b2s[32], fcbs[32], ows[64];
  const int tid = threadIdx.x;
  const int n0 = blockIdx.x * 256;

  ((float4*)fcs)[tid] = ((const float4*)fc_w)[tid];
  if (tid < 32) {
    b2s[tid] = b2[tid];
    fcbs[tid] = fc_b[tid];
  }
  if (tid < 64) ows[tid] = out_w[tid];
  for (int v = tid; v < 2048; v += WG) {
    int row = v >> 3, c4 = v & 7;
    int n = n0 + row;
    float4 val = make_float4(0.f, 0.f, 0.f, 0.f);
    if (n < N) val = ((const float4*)agg2)[(size_t)n * 8 + c4];
    float* p = &hs[row * 33 + c4 * 4];
    p[0] = val.x; p[1] = val.y; p[2] = val.z; p[3] = val.w;
  }
  __syncthreads();

  int n = n0 + tid;
  float acc[32] = {};
  const int base = tid * 33;
#pragma unroll
  for (int k = 0; k < 32; k++) {
    float vk = fmaxf(hs[base + k] + b2s[k], 0.f);
#pragma unroll
    for (int j4 = 0; j4 < 8; j4++) {
      float4 f = *(const float4*)&fcs[k * 32 + j4 * 4];
      acc[j4 * 4 + 0] += vk * f.x;
      acc[j4 * 4 + 1] += vk * f.y;
      acc[j4 * 4 + 2] += vk * f.z;
      acc[j4 * 4 + 3] += vk * f.w;
    }
  }
  float o0 = out_b[0], o1 = out_b[1];
#pragma unroll
  for (int j = 0; j < 32; j++) {
    float t = fmaxf(acc[j] + fcbs[j], 0.f);
    o0 += t * ows[2 * j];
    o1 += t * ows[2 * j + 1];
  }
  if (n < N) ((float2*)out)[n] = make_float2(o0, o1);
}

// ---------------------------------------------------------------------------
extern "C" void kernel_launch(void* const* d_in, const int* in_sizes, int n_in,
                              void* d_out, int out_size, void* d_ws, size_t ws_size,
                              hipStream_t stream) {
  const float* x   = (const float*)d_in[0];
  const int*   ei  = (const int*)d_in[1];
  const float* W1  = (const float*)d_in[2];
  const float* b1  = (const float*)d_in[3];
  const float* W2  = (const float*)d_in[4];
  const float* b2  = (const float*)d_in[5];
  const float* fcw = (const float*)d_in[6];
  const float* fcb = (const float*)d_in[7];
  const float* ow  = (const float*)d_in[8];
  const float* ob  = (const float*)d_in[9];

  const int N  = in_sizes[0] / 128;
  const int E  = in_sizes[1] / 2;
  const int NB = (N + BN - 1) / BN;        // buckets (<= NBMAX)
  const int NC = (E + CHUNK - 1) / CHUNK;  // chunks

  // workspace: flag | pairs(E int2) | bucketTotal(NB) | bucketBase(NB+1) |
  // dinv(N) | [hist(NC*NB) overlapped by ht1(64N), hist dead after mscatter]
  // | agg1(64N) | ht2(32N).  agg2 aliases ht1.
  char* p = (char*)d_ws;
  int* flag = (int*)p;               p += 64;
  int2* pairs = (int2*)p;            p += (size_t)E * sizeof(int2);
  int* bucketTotal = (int*)p;        p += ((size_t)NB + 16) * 4;
  int* bucketBase = (int*)p;         p += ((size_t)NB + 17) * 4;
  float* dinv = (float*)p;           p += (size_t)N * 4;
  p = (char*)(((uintptr_t)p + 63) & ~(uintptr_t)63);
  float* ht1 = (float*)p;            // 64N floats
  int* hist = (int*)p;               // NC*NB ints (fits well inside ht1 region)
  p += (size_t)N * 64 * 4;
  float* agg1 = (float*)p;           p += (size_t)N * 64 * 4;
  float* ht2 = (float*)p;            p += (size_t)N * 32 * 4;
  float* agg2 = ht1;                 // alias: ht1 dead after bagg64
  float* out = (float*)d_out;

  hipLaunchKernelGGL(k_detect, dim3(1), dim3(WG), 0, stream,
                     (const unsigned int*)ei, flag);
  hipLaunchKernelGGL(k_hist, dim3(NC), dim3(WG), 0, stream,
                     ei, flag, hist, NB, E);
  hipLaunchKernelGGL(k_bscan1, dim3(NB), dim3(512), 0, stream,
                     hist, bucketTotal, NB, NC);
  hipLaunchKernelGGL(k_bbase, dim3(1), dim3(1024), 0, stream,
                     bucketTotal, bucketBase, NB);
  hipLaunchKernelGGL(k_mscatter, dim3(NC), dim3(WG), 0, stream,
                     ei, flag, hist, bucketBase, pairs, NB, E);
  hipLaunchKernelGGL(k_bdeg, dim3(NB), dim3(WG), 0, stream,
                     pairs, bucketBase, dinv, N);
  hipLaunchKernelGGL(k_gemm1, dim3((N + 63) / 64), dim3(WG), 0, stream,
                     x, W1, dinv, ht1, N);
  hipLaunchKernelGGL(k_bagg64, dim3(NB), dim3(AGG_T), 0, stream,
                     pairs, bucketBase, dinv, ht1, agg1, N);
  hipLaunchKernelGGL(k_gemm2, dim3((N + 63) / 64), dim3(WG), 0, stream,
                     agg1, b1, W2, dinv, ht2, N);
  hipLaunchKernelGGL(k_bagg32, dim3(NB), dim3(AGG_T), 0, stream,
                     pairs, bucketBase, dinv, ht2, agg2, N);
  hipLaunchKernelGGL(k_final, dim3((N + 255) / 256), dim3(WG), 0, stream,
                     agg2, b2, fcw, fcb, ow, ob, out, N);
}

// Round 4
// 364.872 us; speedup vs baseline: 5.8512x; 5.8512x over previous
//
#include <hip/hip_runtime.h>

#define WG 256
#define BN 128        // nodes per bucket
#define NBMAX 800     // max buckets (N <= 102400)
#define CHUNK 8192    // edges per binning chunk

// ---------------------------------------------------------------------------
// Edge-index dtype probe: int64 little-endian (values < 2^31) => all odd
// 32-bit words of the first 256 entries are 0.
// ---------------------------------------------------------------------------
__global__ __launch_bounds__(WG) void k_detect(const unsigned int* __restrict__ ei,
                                               int* __restrict__ flag) {
  __shared__ int nz;
  if (threadIdx.x == 0) nz = 0;
  __syncthreads();
  unsigned int w = ei[threadIdx.x * 2 + 1];
  if (w != 0u) atomicAdd(&nz, 1);
  __syncthreads();
  if (threadIdx.x == 0) *flag = (nz == 0) ? 1 : 0;  // 1 => int64 layout
}

// ---------------------------------------------------------------------------
// Per-chunk bucket histogram (LDS atomics only): hist[chunk][NB]
// ---------------------------------------------------------------------------
__global__ __launch_bounds__(WG) void k_hist(const int* __restrict__ ei,
                                             const int* __restrict__ flag,
                                             int* __restrict__ hist, int NB, int E) {
  __shared__ int hc[NBMAX];
  const int c = blockIdx.x;
  for (int b = threadIdx.x; b < NB; b += WG) hc[b] = 0;
  __syncthreads();
  const bool i64 = (*flag != 0);
  const int e0 = c * CHUNK;
  for (int i = 0; i < CHUNK; i += WG) {
    int e = e0 + i + threadIdx.x;
    if (e < E) {
      int d = i64 ? ei[2 * (E + e)] : ei[E + e];
      atomicAdd(&hc[d / BN], 1);
    }
  }
  __syncthreads();
  for (int b = threadIdx.x; b < NB; b += WG) hist[(size_t)c * NB + b] = hc[b];
}

// ---------------------------------------------------------------------------
// Per-bucket exclusive scan over chunks (in place); total -> bucketTotal[b]
// ---------------------------------------------------------------------------
__global__ __launch_bounds__(512) void k_bscan1(int* __restrict__ hist,
                                                int* __restrict__ bucketTotal,
                                                int NB, int NC) {
  __shared__ int sh[512];
  const int b = blockIdx.x;
  int carry = 0;
  for (int c0 = 0; c0 < NC; c0 += 512) {
    int c = c0 + (int)threadIdx.x;
    int v = (c < NC) ? hist[(size_t)c * NB + b] : 0;
    sh[threadIdx.x] = v;
    __syncthreads();
    for (int off = 1; off < 512; off <<= 1) {
      int t = (threadIdx.x >= (unsigned)off) ? sh[threadIdx.x - off] : 0;
      __syncthreads();
      sh[threadIdx.x] += t;
      __syncthreads();
    }
    if (c < NC) hist[(size_t)c * NB + b] = carry + sh[threadIdx.x] - v;
    carry += sh[511];
    __syncthreads();
  }
  if (threadIdx.x == 0) bucketTotal[b] = carry;
}

// exclusive scan of bucketTotal -> bucketBase[0..NB]
__global__ __launch_bounds__(1024) void k_bbase(const int* __restrict__ bucketTotal,
                                                int* __restrict__ bucketBase, int NB) {
  __shared__ int sh[1024];
  int carry = 0;
  for (int b0 = 0; b0 < NB; b0 += 1024) {
    int b = b0 + (int)threadIdx.x;
    int v = (b < NB) ? bucketTotal[b] : 0;
    sh[threadIdx.x] = v;
    __syncthreads();
    for (int off = 1; off < 1024; off <<= 1) {
      int t = (threadIdx.x >= (unsigned)off) ? sh[threadIdx.x - off] : 0;
      __syncthreads();
      sh[threadIdx.x] += t;
      __syncthreads();
    }
    if (b < NB) bucketBase[b] = carry + sh[threadIdx.x] - v;
    carry += sh[1023];
    __syncthreads();
  }
  if (threadIdx.x == 0) bucketBase[NB] = carry;
}

// ---------------------------------------------------------------------------
// Multisplit scatter: chunk c writes (src,dst) pairs into its private slice
// of each bucket region. LDS cursors; no global atomics.
// ---------------------------------------------------------------------------
__global__ __launch_bounds__(WG) void k_mscatter(const int* __restrict__ ei,
                                                 const int* __restrict__ flag,
                                                 const int* __restrict__ hist,
                                                 const int* __restrict__ bucketBase,
                                                 int2* __restrict__ pairs,
                                                 int NB, int E) {
  __shared__ int cur[NBMAX];
  const int c = blockIdx.x;
  for (int b = threadIdx.x; b < NB; b += WG)
    cur[b] = bucketBase[b] + hist[(size_t)c * NB + b];
  __syncthreads();
  const bool i64 = (*flag != 0);
  const int e0 = c * CHUNK;
  for (int i = 0; i < CHUNK; i += WG) {
    int e = e0 + i + threadIdx.x;
    if (e < E) {
      int s, d;
      if (i64) { s = ei[2 * e]; d = ei[2 * (E + e)]; }
      else     { s = ei[e];     d = ei[E + e]; }
      int pos = atomicAdd(&cur[d / BN], 1);
      pairs[pos] = make_int2(s, d);
    }
  }
}

// ---------------------------------------------------------------------------
// Per-bucket counting sort: pairs (bucket-grouped) -> perm (node-grouped),
// plus rowptr and dinv. All cursors in LDS; perm writes hit one contiguous
// ~16KB slice per block (L2 write-combined).
// ---------------------------------------------------------------------------
__global__ __launch_bounds__(WG) void k_bsort(const int2* __restrict__ pairs,
                                              const int* __restrict__ bucketBase,
                                              int* __restrict__ perm,
                                              int* __restrict__ rowptr,
                                              float* __restrict__ dinv,
                                              int N, int NB) {
  __shared__ int cnt[BN];
  __shared__ int cur[BN];
  __shared__ int sc[BN];
  const int b = blockIdx.x;
  const int base = b * BN;
  const int t = threadIdx.x;
  if (t < BN) cnt[t] = 0;
  __syncthreads();
  const int beg = bucketBase[b], end = bucketBase[b + 1];
  for (int e = beg + t; e < end; e += WG)
    atomicAdd(&cnt[pairs[e].y - base], 1);
  __syncthreads();
  if (t < BN) sc[t] = cnt[t];
  __syncthreads();
  for (int off = 1; off < BN; off <<= 1) {
    int v = (t < BN && t >= off) ? sc[t - off] : 0;
    __syncthreads();
    if (t < BN) sc[t] += v;
    __syncthreads();
  }
  if (t < BN) {
    int excl = beg + sc[t] - cnt[t];
    cur[t] = excl;
    int n = base + t;
    if (n < N) {
      rowptr[n] = excl;
      dinv[n] = rsqrtf((float)(cnt[t] + 1));  // +1 = self-loop
    }
  }
  if (b == NB - 1 && t == 0) rowptr[N] = end;
  __syncthreads();
  for (int e = beg + t; e < end; e += WG) {
    int2 p = pairs[e];
    int pos = atomicAdd(&cur[p.y - base], 1);
    perm[pos] = p.x;
  }
}

// ---------------------------------------------------------------------------
// GEMM1: ht1[n][64] = (x[n][128] @ W1[128][64]) * dinv[n]
// ---------------------------------------------------------------------------
__global__ __launch_bounds__(WG) void k_gemm1(const float* __restrict__ x,
                                              const float* __restrict__ W1,
                                              const float* __restrict__ dinv,
                                              float* __restrict__ ht1, int N) {
  __shared__ float xs[64 * 128];
  __shared__ float w1s[128 * 64];
  const int tid = threadIdx.x;
  const int n0 = blockIdx.x * 64;

  for (int v = tid; v < 2048; v += WG)
    *(float4*)&w1s[v * 4] = ((const float4*)W1)[v];
  for (int v = tid; v < 2048; v += WG) {
    int row = v >> 5, c4 = v & 31;
    int n = n0 + row;
    float4 val = make_float4(0.f, 0.f, 0.f, 0.f);
    if (n < N) val = ((const float4*)x)[(size_t)n * 32 + c4];
    *(float4*)&xs[row * 128 + ((c4 ^ ((row >> 2) & 3)) << 2)] = val;
  }
  __syncthreads();

  const int cg = tid & 15;
  const int ng = tid >> 4;
  const int ngm = ng & 3;
  float acc[4][4] = {};

#pragma unroll 4
  for (int k4 = 0; k4 < 32; k4++) {
    float4 xa[4], wv[4];
#pragma unroll
    for (int i = 0; i < 4; i++)
      xa[i] = *(const float4*)&xs[(ng * 4 + i) * 128 + ((k4 ^ ngm) << 2)];
#pragma unroll
    for (int kk = 0; kk < 4; kk++)
      wv[kk] = *(const float4*)&w1s[(k4 * 4 + kk) * 64 + cg * 4];
#pragma unroll
    for (int i = 0; i < 4; i++) {
#pragma unroll
      for (int kk = 0; kk < 4; kk++) {
        float a = (kk == 0) ? xa[i].x : (kk == 1) ? xa[i].y : (kk == 2) ? xa[i].z : xa[i].w;
        acc[i][0] += a * wv[kk].x;
        acc[i][1] += a * wv[kk].y;
        acc[i][2] += a * wv[kk].z;
        acc[i][3] += a * wv[kk].w;
      }
    }
  }

#pragma unroll
  for (int i = 0; i < 4; i++) {
    int n = n0 + ng * 4 + i;
    if (n >= N) continue;
    float dv = dinv[n];
    ((float4*)ht1)[(size_t)n * 16 + cg] = make_float4(
        acc[i][0] * dv, acc[i][1] * dv, acc[i][2] * dv, acc[i][3] * dv);
  }
}

// ---------------------------------------------------------------------------
// CSR aggregation, 64 ch: one wave per node, lane = channel.
// agg[n] = dinv[n] * (ht[n] + sum_{s in CSR(n)} ht[s])
// ---------------------------------------------------------------------------
__global__ __launch_bounds__(WG) void k_aggcsr64(const int* __restrict__ rowptr,
                                                 const int* __restrict__ perm,
                                                 const float* __restrict__ dinv,
                                                 const float* __restrict__ ht,
                                                 float* __restrict__ agg, int N) {
  int n = (blockIdx.x * WG + threadIdx.x) >> 6;
  int lane = threadIdx.x & 63;
  if (n >= N) return;
  int beg = rowptr[n], end = rowptr[n + 1];
  float acc = ht[(size_t)n * 64 + lane];
  int j = beg;
  for (; j + 4 <= end; j += 4) {
    int s0 = perm[j], s1 = perm[j + 1], s2 = perm[j + 2], s3 = perm[j + 3];
    float v0 = ht[(size_t)s0 * 64 + lane];
    float v1 = ht[(size_t)s1 * 64 + lane];
    float v2 = ht[(size_t)s2 * 64 + lane];
    float v3 = ht[(size_t)s3 * 64 + lane];
    acc += v0 + v1 + v2 + v3;
  }
  for (; j < end; ++j) acc += ht[(size_t)perm[j] * 64 + lane];
  agg[(size_t)n * 64 + lane] = acc * dinv[n];
}

// 32-ch variant: half-wave per node
__global__ __launch_bounds__(WG) void k_aggcsr32(const int* __restrict__ rowptr,
                                                 const int* __restrict__ perm,
                                                 const float* __restrict__ dinv,
                                                 const float* __restrict__ ht,
                                                 float* __restrict__ agg, int N) {
  int n = (blockIdx.x * WG + threadIdx.x) >> 5;
  int l = threadIdx.x & 31;
  if (n >= N) return;
  int beg = rowptr[n], end = rowptr[n + 1];
  float acc = ht[(size_t)n * 32 + l];
  int j = beg;
  for (; j + 4 <= end; j += 4) {
    int s0 = perm[j], s1 = perm[j + 1], s2 = perm[j + 2], s3 = perm[j + 3];
    acc += ht[(size_t)s0 * 32 + l] + ht[(size_t)s1 * 32 + l] +
           ht[(size_t)s2 * 32 + l] + ht[(size_t)s3 * 32 + l];
  }
  for (; j < end; ++j) acc += ht[(size_t)perm[j] * 32 + l];
  agg[(size_t)n * 32 + l] = acc * dinv[n];
}

// ---------------------------------------------------------------------------
// GEMM2: ht2[n][32] = (relu(agg1[n][64] + b1) @ W2[64][32]) * dinv[n]
// ---------------------------------------------------------------------------
__global__ __launch_bounds__(WG) void k_gemm2(const float* __restrict__ agg1,
                                              const float* __restrict__ b1,
                                              const float* __restrict__ W2,
                                              const float* __restrict__ dinv,
                                              float* __restrict__ ht2, int N) {
  __shared__ float as[64 * 68];
  __shared__ float w2s[64 * 32];
  const int tid = threadIdx.x;
  const int n0 = blockIdx.x * 64;

  for (int v = tid; v < 512; v += WG)
    *(float4*)&w2s[v * 4] = ((const float4*)W2)[v];
  for (int v = tid; v < 1024; v += WG) {
    int row = v >> 4, c4 = v & 15;
    int n = n0 + row;
    float4 val = make_float4(0.f, 0.f, 0.f, 0.f);
    if (n < N) {
      float4 g = ((const float4*)agg1)[(size_t)n * 16 + c4];
      float4 bb = ((const float4*)b1)[c4];
      val.x = fmaxf(g.x + bb.x, 0.f);
      val.y = fmaxf(g.y + bb.y, 0.f);
      val.z = fmaxf(g.z + bb.z, 0.f);
      val.w = fmaxf(g.w + bb.w, 0.f);
    }
    *(float4*)&as[row * 68 + c4 * 4] = val;
  }
  __syncthreads();

  const int cg = tid & 15;
  const int ng = tid >> 4;
  float acc[4][2] = {};

#pragma unroll 4
  for (int k4 = 0; k4 < 16; k4++) {
    float4 xa[4];
    float2 wv[4];
#pragma unroll
    for (int i = 0; i < 4; i++)
      xa[i] = *(const float4*)&as[(ng * 4 + i) * 68 + k4 * 4];
#pragma unroll
    for (int kk = 0; kk < 4; kk++)
      wv[kk] = *(const float2*)&w2s[(k4 * 4 + kk) * 32 + cg * 2];
#pragma unroll
    for (int i = 0; i < 4; i++) {
#pragma unroll
      for (int kk = 0; kk < 4; kk++) {
        float a = (kk == 0) ? xa[i].x : (kk == 1) ? xa[i].y : (kk == 2) ? xa[i].z : xa[i].w;
        acc[i][0] += a * wv[kk].x;
        acc[i][1] += a * wv[kk].y;
      }
    }
  }

#pragma unroll
  for (int i = 0; i < 4; i++) {
    int n = n0 + ng * 4 + i;
    if (n >= N) continue;
    float dv = dinv[n];
    ((float2*)ht2)[(size_t)n * 16 + cg] =
        make_float2(acc[i][0] * dv, acc[i][1] * dv);
  }
}

// ---------------------------------------------------------------------------
// Final head: out[n][2] = (relu(relu(agg2[n]+b2) @ fc_w + fc_b)) @ out_w + out_b
// ---------------------------------------------------------------------------
__global__ __launch_bounds__(WG) void k_final(const float* __restrict__ agg2,
                                              const float* __restrict__ b2,
                                              const float* __restrict__ fc_w,
                                              const float* __restrict__ fc_b,
                                              const float* __restrict__ out_w,
                                              const float* __restrict__ out_b,
                                              float* __restrict__ out, int N) {
  __shared__ float hs[256 * 33];
  __shared__ float fcs[32 * 32];
  __shared__ float b2s[32], fcbs[32], ows[64];
  const int tid = threadIdx.x;
  const int n0 = blockIdx.x * 256;

  ((float4*)fcs)[tid] = ((const float4*)fc_w)[tid];
  if (tid < 32) {
    b2s[tid] = b2[tid];
    fcbs[tid] = fc_b[tid];
  }
  if (tid < 64) ows[tid] = out_w[tid];
  for (int v = tid; v < 2048; v += WG) {
    int row = v >> 3, c4 = v & 7;
    int n = n0 + row;
    float4 val = make_float4(0.f, 0.f, 0.f, 0.f);
    if (n < N) val = ((const float4*)agg2)[(size_t)n * 8 + c4];
    float* p = &hs[row * 33 + c4 * 4];
    p[0] = val.x; p[1] = val.y; p[2] = val.z; p[3] = val.w;
  }
  __syncthreads();

  int n = n0 + tid;
  float acc[32] = {};
  const int base = tid * 33;
#pragma unroll
  for (int k = 0; k < 32; k++) {
    float vk = fmaxf(hs[base + k] + b2s[k], 0.f);
#pragma unroll
    for (int j4 = 0; j4 < 8; j4++) {
      float4 f = *(const float4*)&fcs[k * 32 + j4 * 4];
      acc[j4 * 4 + 0] += vk * f.x;
      acc[j4 * 4 + 1] += vk * f.y;
      acc[j4 * 4 + 2] += vk * f.z;
      acc[j4 * 4 + 3] += vk * f.w;
    }
  }
  float o0 = out_b[0], o1 = out_b[1];
#pragma unroll
  for (int j = 0; j < 32; j++) {
    float t = fmaxf(acc[j] + fcbs[j], 0.f);
    o0 += t * ows[2 * j];
    o1 += t * ows[2 * j + 1];
  }
  if (n < N) ((float2*)out)[n] = make_float2(o0, o1);
}

// ---------------------------------------------------------------------------
extern "C" void kernel_launch(void* const* d_in, const int* in_sizes, int n_in,
                              void* d_out, int out_size, void* d_ws, size_t ws_size,
                              hipStream_t stream) {
  const float* x   = (const float*)d_in[0];
  const int*   ei  = (const int*)d_in[1];
  const float* W1  = (const float*)d_in[2];
  const float* b1  = (const float*)d_in[3];
  const float* W2  = (const float*)d_in[4];
  const float* b2  = (const float*)d_in[5];
  const float* fcw = (const float*)d_in[6];
  const float* fcb = (const float*)d_in[7];
  const float* ow  = (const float*)d_in[8];
  const float* ob  = (const float*)d_in[9];

  const int N  = in_sizes[0] / 128;
  const int E  = in_sizes[1] / 2;
  const int NB = (N + BN - 1) / BN;        // buckets (<= NBMAX)
  const int NC = (E + CHUNK - 1) / CHUNK;  // chunks

  // workspace:
  // flag | pairsRegion (max(E int2, 64N f)): pairs -> ht1 -> agg2 |
  // perm(E) | rowptr(N+4) | dinv(N) | bucketTotal | bucketBase | hist(NC*NB)
  // | agg1(64N) | ht2(32N)
  char* p = (char*)d_ws;
  int* flag = (int*)p;               p += 64;
  size_t pairsBytes = (size_t)E * 8;
  size_t ht1Bytes   = (size_t)N * 64 * 4;
  size_t regBytes   = (pairsBytes > ht1Bytes ? pairsBytes : ht1Bytes) + 256;
  int2* pairs = (int2*)p;
  float* ht1  = (float*)p;
  float* agg2 = (float*)p;           p += regBytes;
  int* perm = (int*)p;               p += (size_t)E * 4 + 64;
  int* rowptr = (int*)p;             p += ((size_t)N + 4) * 4;
  float* dinv = (float*)p;           p += (size_t)N * 4 + 64;
  int* bucketTotal = (int*)p;        p += ((size_t)NB + 16) * 4;
  int* bucketBase = (int*)p;         p += ((size_t)NB + 17) * 4;
  p = (char*)(((uintptr_t)p + 63) & ~(uintptr_t)63);
  int* hist = (int*)p;               p += (size_t)NC * NB * 4 + 64;
  p = (char*)(((uintptr_t)p + 63) & ~(uintptr_t)63);
  float* agg1 = (float*)p;           p += (size_t)N * 64 * 4;
  float* ht2 = (float*)p;            p += (size_t)N * 32 * 4;
  float* out = (float*)d_out;

  hipLaunchKernelGGL(k_detect, dim3(1), dim3(WG), 0, stream,
                     (const unsigned int*)ei, flag);
  hipLaunchKernelGGL(k_hist, dim3(NC), dim3(WG), 0, stream,
                     ei, flag, hist, NB, E);
  hipLaunchKernelGGL(k_bscan1, dim3(NB), dim3(512), 0, stream,
                     hist, bucketTotal, NB, NC);
  hipLaunchKernelGGL(k_bbase, dim3(1), dim3(1024), 0, stream,
                     bucketTotal, bucketBase, NB);
  hipLaunchKernelGGL(k_mscatter, dim3(NC), dim3(WG), 0, stream,
                     ei, flag, hist, bucketBase, pairs, NB, E);
  hipLaunchKernelGGL(k_bsort, dim3(NB), dim3(WG), 0, stream,
                     pairs, bucketBase, perm, rowptr, dinv, N, NB);
  hipLaunchKernelGGL(k_gemm1, dim3((N + 63) / 64), dim3(WG), 0, stream,
                     x, W1, dinv, ht1, N);
  {
    long long tot = (long long)N * 64;
    hipLaunchKernelGGL(k_aggcsr64, dim3((int)((tot + WG - 1) / WG)), dim3(WG), 0,
                       stream, rowptr, perm, dinv, ht1, agg1, N);
  }
  hipLaunchKernelGGL(k_gemm2, dim3((N + 63) / 64), dim3(WG), 0, stream,
                     agg1, b1, W2, dinv, ht2, N);
  {
    long long tot = (long long)N * 32;
    hipLaunchKernelGGL(k_aggcsr32, dim3((int)((tot + WG - 1) / WG)), dim3(WG), 0,
                       stream, rowptr, perm, dinv, ht2, agg2, N);
  }
  hipLaunchKernelGGL(k_final, dim3((N + 255) / 256), dim3(WG), 0, stream,
                     agg2, b2, fcw, fcb, ow, ob, out, N);
}

// Round 5
// 304.261 us; speedup vs baseline: 7.0169x; 1.1992x over previous
//
#include <hip/hip_runtime.h>

#define WG 256
#define BN 128        // nodes per bucket
#define NBMAX 800     // max buckets (N <= 102400)
#define CHUNK 8192    // edges per binning chunk

typedef unsigned int uint32;

__device__ inline ushort f2bf(float f) {  // fp32 -> bf16 RNE
  uint32 u = __float_as_uint(f);
  return (ushort)((u + 0x7fffu + ((u >> 16) & 1u)) >> 16);
}
__device__ inline float bflo(uint32 v) { return __uint_as_float(v << 16); }
__device__ inline float bfhi(uint32 v) { return __uint_as_float(v & 0xffff0000u); }

// ---------------------------------------------------------------------------
// Edge-index dtype probe: int64 little-endian (values < 2^31) => all odd
// 32-bit words of the first 256 entries are 0.
// ---------------------------------------------------------------------------
__global__ __launch_bounds__(WG) void k_detect(const unsigned int* __restrict__ ei,
                                               int* __restrict__ flag) {
  __shared__ int nz;
  if (threadIdx.x == 0) nz = 0;
  __syncthreads();
  unsigned int w = ei[threadIdx.x * 2 + 1];
  if (w != 0u) atomicAdd(&nz, 1);
  __syncthreads();
  if (threadIdx.x == 0) *flag = (nz == 0) ? 1 : 0;  // 1 => int64 layout
}

// ---------------------------------------------------------------------------
// Per-chunk bucket histogram (LDS atomics only): hist[chunk][NB]
// ---------------------------------------------------------------------------
__global__ __launch_bounds__(WG) void k_hist(const int* __restrict__ ei,
                                             const int* __restrict__ flag,
                                             int* __restrict__ hist, int NB, int E) {
  __shared__ int hc[NBMAX];
  const int c = blockIdx.x;
  for (int b = threadIdx.x; b < NB; b += WG) hc[b] = 0;
  __syncthreads();
  const bool i64 = (*flag != 0);
  const int e0 = c * CHUNK;
  for (int i = 0; i < CHUNK; i += WG) {
    int e = e0 + i + threadIdx.x;
    if (e < E) {
      int d = i64 ? ei[2 * (E + e)] : ei[E + e];
      atomicAdd(&hc[d / BN], 1);
    }
  }
  __syncthreads();
  for (int b = threadIdx.x; b < NB; b += WG) hist[(size_t)c * NB + b] = hc[b];
}

// ---------------------------------------------------------------------------
// Per-bucket exclusive scan over chunks (in place); total -> bucketTotal[b]
// ---------------------------------------------------------------------------
__global__ __launch_bounds__(512) void k_bscan1(int* __restrict__ hist,
                                                int* __restrict__ bucketTotal,
                                                int NB, int NC) {
  __shared__ int sh[512];
  const int b = blockIdx.x;
  int carry = 0;
  for (int c0 = 0; c0 < NC; c0 += 512) {
    int c = c0 + (int)threadIdx.x;
    int v = (c < NC) ? hist[(size_t)c * NB + b] : 0;
    sh[threadIdx.x] = v;
    __syncthreads();
    for (int off = 1; off < 512; off <<= 1) {
      int t = (threadIdx.x >= (unsigned)off) ? sh[threadIdx.x - off] : 0;
      __syncthreads();
      sh[threadIdx.x] += t;
      __syncthreads();
    }
    if (c < NC) hist[(size_t)c * NB + b] = carry + sh[threadIdx.x] - v;
    carry += sh[511];
    __syncthreads();
  }
  if (threadIdx.x == 0) bucketTotal[b] = carry;
}

// exclusive scan of bucketTotal -> bucketBase[0..NB]
__global__ __launch_bounds__(1024) void k_bbase(const int* __restrict__ bucketTotal,
                                                int* __restrict__ bucketBase, int NB) {
  __shared__ int sh[1024];
  int carry = 0;
  for (int b0 = 0; b0 < NB; b0 += 1024) {
    int b = b0 + (int)threadIdx.x;
    int v = (b < NB) ? bucketTotal[b] : 0;
    sh[threadIdx.x] = v;
    __syncthreads();
    for (int off = 1; off < 1024; off <<= 1) {
      int t = (threadIdx.x >= (unsigned)off) ? sh[threadIdx.x - off] : 0;
      __syncthreads();
      sh[threadIdx.x] += t;
      __syncthreads();
    }
    if (b < NB) bucketBase[b] = carry + sh[threadIdx.x] - v;
    carry += sh[1023];
    __syncthreads();
  }
  if (threadIdx.x == 0) bucketBase[NB] = carry;
}

// ---------------------------------------------------------------------------
// Multisplit scatter: chunk c writes packed (src<<7 | dst%BN) into its
// private slice of each bucket region. LDS cursors; no global atomics.
// ---------------------------------------------------------------------------
__global__ __launch_bounds__(WG) void k_mscatter(const int* __restrict__ ei,
                                                 const int* __restrict__ flag,
                                                 const int* __restrict__ hist,
                                                 const int* __restrict__ bucketBase,
                                                 uint32* __restrict__ pairs,
                                                 int NB, int E) {
  __shared__ int cur[NBMAX];
  const int c = blockIdx.x;
  for (int b = threadIdx.x; b < NB; b += WG)
    cur[b] = bucketBase[b] + hist[(size_t)c * NB + b];
  __syncthreads();
  const bool i64 = (*flag != 0);
  const int e0 = c * CHUNK;
  for (int i = 0; i < CHUNK; i += WG) {
    int e = e0 + i + threadIdx.x;
    if (e < E) {
      int s, d;
      if (i64) { s = ei[2 * e]; d = ei[2 * (E + e)]; }
      else     { s = ei[e];     d = ei[E + e]; }
      int pos = atomicAdd(&cur[d / BN], 1);
      pairs[pos] = ((uint32)s << 7) | (uint32)(d & (BN - 1));
    }
  }
}

// ---------------------------------------------------------------------------
// Per-bucket counting sort: packed pairs -> perm, rowptr, dinv.
// ---------------------------------------------------------------------------
__global__ __launch_bounds__(WG) void k_bsort(const uint32* __restrict__ pairs,
                                              const int* __restrict__ bucketBase,
                                              int* __restrict__ perm,
                                              int* __restrict__ rowptr,
                                              float* __restrict__ dinv,
                                              int N, int NB) {
  __shared__ int cnt[BN];
  __shared__ int cur[BN];
  __shared__ int sc[BN];
  const int b = blockIdx.x;
  const int t = threadIdx.x;
  if (t < BN) cnt[t] = 0;
  __syncthreads();
  const int beg = bucketBase[b], end = bucketBase[b + 1];
  for (int e = beg + t; e < end; e += WG)
    atomicAdd(&cnt[pairs[e] & (BN - 1)], 1);
  __syncthreads();
  if (t < BN) sc[t] = cnt[t];
  __syncthreads();
  for (int off = 1; off < BN; off <<= 1) {
    int v = (t < BN && t >= off) ? sc[t - off] : 0;
    __syncthreads();
    if (t < BN) sc[t] += v;
    __syncthreads();
  }
  if (t < BN) {
    int excl = beg + sc[t] - cnt[t];
    cur[t] = excl;
    int n = b * BN + t;
    if (n < N) {
      rowptr[n] = excl;
      dinv[n] = rsqrtf((float)(cnt[t] + 1));  // +1 = self-loop
    }
  }
  if (b == NB - 1 && t == 0) rowptr[N] = end;
  __syncthreads();
  for (int e = beg + t; e < end; e += WG) {
    uint32 p = pairs[e];
    int pos = atomicAdd(&cur[p & (BN - 1)], 1);
    perm[pos] = (int)(p >> 7);
  }
}

// ---------------------------------------------------------------------------
// GEMM1: ht1[n][64] = bf16( (x[n][128] @ W1[128][64]) * dinv[n] )
// ---------------------------------------------------------------------------
__global__ __launch_bounds__(WG) void k_gemm1(const float* __restrict__ x,
                                              const float* __restrict__ W1,
                                              const float* __restrict__ dinv,
                                              uint32* __restrict__ ht1, int N) {
  __shared__ float xs[64 * 128];
  __shared__ float w1s[128 * 64];
  const int tid = threadIdx.x;
  const int n0 = blockIdx.x * 64;

  for (int v = tid; v < 2048; v += WG)
    *(float4*)&w1s[v * 4] = ((const float4*)W1)[v];
  for (int v = tid; v < 2048; v += WG) {
    int row = v >> 5, c4 = v & 31;
    int n = n0 + row;
    float4 val = make_float4(0.f, 0.f, 0.f, 0.f);
    if (n < N) val = ((const float4*)x)[(size_t)n * 32 + c4];
    *(float4*)&xs[row * 128 + ((c4 ^ ((row >> 2) & 3)) << 2)] = val;
  }
  __syncthreads();

  const int cg = tid & 15;
  const int ng = tid >> 4;
  const int ngm = ng & 3;
  float acc[4][4] = {};

#pragma unroll 4
  for (int k4 = 0; k4 < 32; k4++) {
    float4 xa[4], wv[4];
#pragma unroll
    for (int i = 0; i < 4; i++)
      xa[i] = *(const float4*)&xs[(ng * 4 + i) * 128 + ((k4 ^ ngm) << 2)];
#pragma unroll
    for (int kk = 0; kk < 4; kk++)
      wv[kk] = *(const float4*)&w1s[(k4 * 4 + kk) * 64 + cg * 4];
#pragma unroll
    for (int i = 0; i < 4; i++) {
#pragma unroll
      for (int kk = 0; kk < 4; kk++) {
        float a = (kk == 0) ? xa[i].x : (kk == 1) ? xa[i].y : (kk == 2) ? xa[i].z : xa[i].w;
        acc[i][0] += a * wv[kk].x;
        acc[i][1] += a * wv[kk].y;
        acc[i][2] += a * wv[kk].z;
        acc[i][3] += a * wv[kk].w;
      }
    }
  }

#pragma unroll
  for (int i = 0; i < 4; i++) {
    int n = n0 + ng * 4 + i;
    if (n >= N) continue;
    float dv = dinv[n];
    uint32 u01 = ((uint32)f2bf(acc[i][1] * dv) << 16) | f2bf(acc[i][0] * dv);
    uint32 u23 = ((uint32)f2bf(acc[i][3] * dv) << 16) | f2bf(acc[i][2] * dv);
    ((uint2*)ht1)[(size_t)n * 16 + cg] = make_uint2(u01, u23);
  }
}

// ---------------------------------------------------------------------------
// CSR aggregation, 64 ch bf16: wave per node; 2 edges per step; fp32 accum.
// ---------------------------------------------------------------------------
__global__ __launch_bounds__(WG) void k_agg64b(const int* __restrict__ rowptr,
                                               const int* __restrict__ perm,
                                               const float* __restrict__ dinv,
                                               const uint32* __restrict__ ht,
                                               float* __restrict__ agg, int N) {
  int n = (blockIdx.x * WG + threadIdx.x) >> 6;
  int lane = threadIdx.x & 63;
  if (n >= N) return;
  const int sub = lane >> 5;   // which edge of the pair
  const int cp = lane & 31;    // channel-pair (2 ch per lane)
  int beg = rowptr[n], end = rowptr[n + 1];
  float a0 = 0.f, a1 = 0.f;
  if (sub == 0) {  // self-loop term
    uint32 v = ht[(size_t)n * 32 + cp];
    a0 += bflo(v); a1 += bfhi(v);
  }
  int j = beg;
  for (; j + 8 <= end; j += 8) {  // 8 edges per iteration
    int s0 = perm[j + sub];
    int s1 = perm[j + 2 + sub];
    int s2 = perm[j + 4 + sub];
    int s3 = perm[j + 6 + sub];
    uint32 v0 = ht[(size_t)s0 * 32 + cp];
    uint32 v1 = ht[(size_t)s1 * 32 + cp];
    uint32 v2 = ht[(size_t)s2 * 32 + cp];
    uint32 v3 = ht[(size_t)s3 * 32 + cp];
    a0 += bflo(v0) + bflo(v1) + bflo(v2) + bflo(v3);
    a1 += bfhi(v0) + bfhi(v1) + bfhi(v2) + bfhi(v3);
  }
  for (; j + 2 <= end; j += 2) {
    int s = perm[j + sub];
    uint32 v = ht[(size_t)s * 32 + cp];
    a0 += bflo(v); a1 += bfhi(v);
  }
  if (j < end && sub == 0) {  // odd remainder
    int s = perm[j];
    uint32 v = ht[(size_t)s * 32 + cp];
    a0 += bflo(v); a1 += bfhi(v);
  }
  a0 += __shfl(a0, lane ^ 32, 64);
  a1 += __shfl(a1, lane ^ 32, 64);
  if (sub == 0) {
    float dv = dinv[n];
    ((float2*)agg)[(size_t)n * 32 + cp] = make_float2(a0 * dv, a1 * dv);
  }
}

// 32-ch bf16 variant: 4 edges per step.
__global__ __launch_bounds__(WG) void k_agg32b(const int* __restrict__ rowptr,
                                               const int* __restrict__ perm,
                                               const float* __restrict__ dinv,
                                               const uint32* __restrict__ ht,
                                               float* __restrict__ agg, int N) {
  int n = (blockIdx.x * WG + threadIdx.x) >> 6;
  int lane = threadIdx.x & 63;
  if (n >= N) return;
  const int sub = lane >> 4;   // 0..3: which edge of the quad
  const int cp = lane & 15;    // channel-pair
  int beg = rowptr[n], end = rowptr[n + 1];
  float a0 = 0.f, a1 = 0.f;
  if (sub == 0) {  // self-loop term
    uint32 v = ht[(size_t)n * 16 + cp];
    a0 += bflo(v); a1 += bfhi(v);
  }
  int j = beg;
  for (; j + 8 <= end; j += 8) {  // 8 edges per iteration
    int s0 = perm[j + sub];
    int s1 = perm[j + 4 + sub];
    uint32 v0 = ht[(size_t)s0 * 16 + cp];
    uint32 v1 = ht[(size_t)s1 * 16 + cp];
    a0 += bflo(v0) + bflo(v1);
    a1 += bfhi(v0) + bfhi(v1);
  }
  for (; j + 4 <= end; j += 4) {
    int s = perm[j + sub];
    uint32 v = ht[(size_t)s * 16 + cp];
    a0 += bflo(v); a1 += bfhi(v);
  }
  int rem = end - j;
  if (sub < rem) {
    int s = perm[j + sub];
    uint32 v = ht[(size_t)s * 16 + cp];
    a0 += bflo(v); a1 += bfhi(v);
  }
  a0 += __shfl(a0, lane ^ 16, 64);
  a1 += __shfl(a1, lane ^ 16, 64);
  a0 += __shfl(a0, lane ^ 32, 64);
  a1 += __shfl(a1, lane ^ 32, 64);
  if (sub == 0) {
    float dv = dinv[n];
    ((float2*)agg)[(size_t)n * 16 + cp] = make_float2(a0 * dv, a1 * dv);
  }
}

// ---------------------------------------------------------------------------
// GEMM2: ht2[n][32] = bf16( (relu(agg1[n][64] + b1) @ W2[64][32]) * dinv[n] )
// ---------------------------------------------------------------------------
__global__ __launch_bounds__(WG) void k_gemm2(const float* __restrict__ agg1,
                                              const float* __restrict__ b1,
                                              const float* __restrict__ W2,
                                              const float* __restrict__ dinv,
                                              uint32* __restrict__ ht2, int N) {
  __shared__ float as[64 * 68];
  __shared__ float w2s[64 * 32];
  const int tid = threadIdx.x;
  const int n0 = blockIdx.x * 64;

  for (int v = tid; v < 512; v += WG)
    *(float4*)&w2s[v * 4] = ((const float4*)W2)[v];
  for (int v = tid; v < 1024; v += WG) {
    int row = v >> 4, c4 = v & 15;
    int n = n0 + row;
    float4 val = make_float4(0.f, 0.f, 0.f, 0.f);
    if (n < N) {
      float4 g = ((const float4*)agg1)[(size_t)n * 16 + c4];
      float4 bb = ((const float4*)b1)[c4];
      val.x = fmaxf(g.x + bb.x, 0.f);
      val.y = fmaxf(g.y + bb.y, 0.f);
      val.z = fmaxf(g.z + bb.z, 0.f);
      val.w = fmaxf(g.w + bb.w, 0.f);
    }
    *(float4*)&as[row * 68 + c4 * 4] = val;
  }
  __syncthreads();

  const int cg = tid & 15;
  const int ng = tid >> 4;
  float acc[4][2] = {};

#pragma unroll 4
  for (int k4 = 0; k4 < 16; k4++) {
    float4 xa[4];
    float2 wv[4];
#pragma unroll
    for (int i = 0; i < 4; i++)
      xa[i] = *(const float4*)&as[(ng * 4 + i) * 68 + k4 * 4];
#pragma unroll
    for (int kk = 0; kk < 4; kk++)
      wv[kk] = *(const float2*)&w2s[(k4 * 4 + kk) * 32 + cg * 2];
#pragma unroll
    for (int i = 0; i < 4; i++) {
#pragma unroll
      for (int kk = 0; kk < 4; kk++) {
        float a = (kk == 0) ? xa[i].x : (kk == 1) ? xa[i].y : (kk == 2) ? xa[i].z : xa[i].w;
        acc[i][0] += a * wv[kk].x;
        acc[i][1] += a * wv[kk].y;
      }
    }
  }

#pragma unroll
  for (int i = 0; i < 4; i++) {
    int n = n0 + ng * 4 + i;
    if (n >= N) continue;
    float dv = dinv[n];
    ht2[(size_t)n * 16 + cg] =
        ((uint32)f2bf(acc[i][1] * dv) << 16) | f2bf(acc[i][0] * dv);
  }
}

// ---------------------------------------------------------------------------
// Final head: out[n][2] = (relu(relu(agg2[n]+b2) @ fc_w + fc_b)) @ out_w + out_b
// ---------------------------------------------------------------------------
__global__ __launch_bounds__(WG) void k_final(const float* __restrict__ agg2,
                                              const float* __restrict__ b2,
                                              const float* __restrict__ fc_w,
                                              const float* __restrict__ fc_b,
                                              const float* __restrict__ out_w,
                                              const float* __restrict__ out_b,
                                              float* __restrict__ out, int N) {
  __shared__ float hs[256 * 33];
  __shared__ float fcs[32 * 32];
  __shared__ float b2s[32], fcbs[32], ows[64];
  const int tid = threadIdx.x;
  const int n0 = blockIdx.x * 256;

  ((float4*)fcs)[tid] = ((const float4*)fc_w)[tid];
  if (tid < 32) {
    b2s[tid] = b2[tid];
    fcbs[tid] = fc_b[tid];
  }
  if (tid < 64) ows[tid] = out_w[tid];
  for (int v = tid; v < 2048; v += WG) {
    int row = v >> 3, c4 = v & 7;
    int n = n0 + row;
    float4 val = make_float4(0.f, 0.f, 0.f, 0.f);
    if (n < N) val = ((const float4*)agg2)[(size_t)n * 8 + c4];
    float* p = &hs[row * 33 + c4 * 4];
    p[0] = val.x; p[1] = val.y; p[2] = val.z; p[3] = val.w;
  }
  __syncthreads();

  int n = n0 + tid;
  float acc[32] = {};
  const int base = tid * 33;
#pragma unroll
  for (int k = 0; k < 32; k++) {
    float vk = fmaxf(hs[base + k] + b2s[k], 0.f);
#pragma unroll
    for (int j4 = 0; j4 < 8; j4++) {
      float4 f = *(const float4*)&fcs[k * 32 + j4 * 4];
      acc[j4 * 4 + 0] += vk * f.x;
      acc[j4 * 4 + 1] += vk * f.y;
      acc[j4 * 4 + 2] += vk * f.z;
      acc[j4 * 4 + 3] += vk * f.w;
    }
  }
  float o0 = out_b[0], o1 = out_b[1];
#pragma unroll
  for (int j = 0; j < 32; j++) {
    float t = fmaxf(acc[j] + fcbs[j], 0.f);
    o0 += t * ows[2 * j];
    o1 += t * ows[2 * j + 1];
  }
  if (n < N) ((float2*)out)[n] = make_float2(o0, o1);
}

// ---------------------------------------------------------------------------
extern "C" void kernel_launch(void* const* d_in, const int* in_sizes, int n_in,
                              void* d_out, int out_size, void* d_ws, size_t ws_size,
                              hipStream_t stream) {
  const float* x   = (const float*)d_in[0];
  const int*   ei  = (const int*)d_in[1];
  const float* W1  = (const float*)d_in[2];
  const float* b1  = (const float*)d_in[3];
  const float* W2  = (const float*)d_in[4];
  const float* b2  = (const float*)d_in[5];
  const float* fcw = (const float*)d_in[6];
  const float* fcb = (const float*)d_in[7];
  const float* ow  = (const float*)d_in[8];
  const float* ob  = (const float*)d_in[9];

  const int N  = in_sizes[0] / 128;
  const int E  = in_sizes[1] / 2;
  const int NB = (N + BN - 1) / BN;        // buckets (<= NBMAX)
  const int NC = (E + CHUNK - 1) / CHUNK;  // chunks

  // workspace (no aliasing): flag | pairs(E) | perm(E) | rowptr(N+4) |
  // dinv(N) | bucketTotal/Base | hist(NC*NB) | ht1(32N u32) | agg1(64N f) |
  // ht2(16N u32) | agg2(32N f)
  char* p = (char*)d_ws;
  int* flag = (int*)p;               p += 64;
  uint32* pairs = (uint32*)p;        p += (size_t)E * 4 + 64;
  int* perm = (int*)p;               p += (size_t)E * 4 + 64;
  int* rowptr = (int*)p;             p += ((size_t)N + 4) * 4;
  float* dinv = (float*)p;           p += (size_t)N * 4 + 64;
  int* bucketTotal = (int*)p;        p += ((size_t)NB + 16) * 4;
  int* bucketBase = (int*)p;         p += ((size_t)NB + 17) * 4;
  p = (char*)(((uintptr_t)p + 63) & ~(uintptr_t)63);
  int* hist = (int*)p;               p += (size_t)NC * NB * 4 + 64;
  p = (char*)(((uintptr_t)p + 63) & ~(uintptr_t)63);
  uint32* ht1 = (uint32*)p;          p += (size_t)N * 32 * 4;
  float* agg1 = (float*)p;           p += (size_t)N * 64 * 4;
  uint32* ht2 = (uint32*)p;          p += (size_t)N * 16 * 4;
  float* agg2 = (float*)p;           p += (size_t)N * 32 * 4;
  float* out = (float*)d_out;

  hipLaunchKernelGGL(k_detect, dim3(1), dim3(WG), 0, stream,
                     (const unsigned int*)ei, flag);
  hipLaunchKernelGGL(k_hist, dim3(NC), dim3(WG), 0, stream,
                     ei, flag, hist, NB, E);
  hipLaunchKernelGGL(k_bscan1, dim3(NB), dim3(512), 0, stream,
                     hist, bucketTotal, NB, NC);
  hipLaunchKernelGGL(k_bbase, dim3(1), dim3(1024), 0, stream,
                     bucketTotal, bucketBase, NB);
  hipLaunchKernelGGL(k_mscatter, dim3(NC), dim3(WG), 0, stream,
                     ei, flag, hist, bucketBase, pairs, NB, E);
  hipLaunchKernelGGL(k_bsort, dim3(NB), dim3(WG), 0, stream,
                     pairs, bucketBase, perm, rowptr, dinv, N, NB);
  hipLaunchKernelGGL(k_gemm1, dim3((N + 63) / 64), dim3(WG), 0, stream,
                     x, W1, dinv, ht1, N);
  {
    long long tot = (long long)N * 64;
    hipLaunchKernelGGL(k_agg64b, dim3((int)((tot + WG - 1) / WG)), dim3(WG), 0,
                       stream, rowptr, perm, dinv, ht1, agg1, N);
  }
  hipLaunchKernelGGL(k_gemm2, dim3((N + 63) / 64), dim3(WG), 0, stream,
                     agg1, b1, W2, dinv, ht2, N);
  {
    long long tot = (long long)N * 64;
    hipLaunchKernelGGL(k_agg32b, dim3((int)((tot + WG - 1) / WG)), dim3(WG), 0,
                       stream, rowptr, perm, dinv, ht2, agg2, N);
  }
  hipLaunchKernelGGL(k_final, dim3((N + 255) / 256), dim3(WG), 0, stream,
                     agg2, b2, fcw, fcb, ow, ob, out, N);
}